// Round 3
// baseline (186.649 us; speedup 1.0000x reference)
//
#include <hip/hip_runtime.h>
#include <stdint.h>
#include <math.h>

#define KDIM 2304   // 9 * 256

typedef __attribute__((ext_vector_type(8))) short bf16x8;
typedef __attribute__((ext_vector_type(4))) float f32x4;

__device__ inline unsigned short f2bf(float f) {
  union { float f; unsigned int u; } v; v.f = f;
  unsigned int u = v.u;
  unsigned int r = (u + 0x7FFFu + ((u >> 16) & 1u)) >> 16;
  return (unsigned short)r;
}
__device__ inline float bf2f(unsigned short h) {
  union { unsigned int u; float f; } v; v.u = ((unsigned int)h) << 16;
  return v.f;
}

__device__ inline void gl2lds16(const void* g, void* l) {
  __builtin_amdgcn_global_load_lds((const __attribute__((address_space(1))) void*)g,
                                   (__attribute__((address_space(3))) void*)l,
                                   16, 0, 0);
}

// ---------------------------------------------------------------------------
// Kernel 1: x (B,C,H,W) fp32 -> xTb (B,H,W,C) bf16
// ---------------------------------------------------------------------------
__global__ __launch_bounds__(256) void k_transpose(const float* __restrict__ x,
                                                   unsigned short* __restrict__ xTb) {
  __shared__ float tile[32][33];
  int t = threadIdx.x;
  int tx = t & 31, ty = t >> 5;
  int p0 = blockIdx.x * 32;
  int c0 = blockIdx.y * 32;
  int b  = blockIdx.z;
  const float* xb = x + ((size_t)b << 20);
#pragma unroll
  for (int i = 0; i < 4; ++i) {
    int c = c0 + ty + i * 8;
    tile[ty + i * 8][tx] = xb[((size_t)c << 12) + p0 + tx];
  }
  __syncthreads();
  unsigned short* ob = xTb + ((size_t)b << 20);
#pragma unroll
  for (int i = 0; i < 4; ++i) {
    int p = p0 + ty + i * 8;
    ob[(((size_t)p) << 8) + c0 + tx] = f2bf(tile[tx][ty + i * 8]);
  }
}

// ---------------------------------------------------------------------------
// Kernel 2: weight prep.
// ---------------------------------------------------------------------------
__global__ __launch_bounds__(256) void k_wprep(const float* __restrict__ dcn_w,
                                               const float* __restrict__ offset_w,
                                               unsigned short* __restrict__ Wb,
                                               unsigned short* __restrict__ Wob,
                                               unsigned short* __restrict__ zp) {
  int gid = blockIdx.x * 256 + threadIdx.x;
  const int N1 = 256 * KDIM;
  const int N2 = 32 * KDIM;
  if (gid < N1) {
    int o = gid / KDIM, k = gid % KDIM;
    int kidx = k >> 8, c = k & 255;
    Wb[gid] = f2bf(dcn_w[((size_t)(o * 256 + c)) * 9 + kidx]);
  } else if (gid < N1 + N2) {
    int g = gid - N1;
    int ch = g / KDIM, k = g % KDIM;
    int kidx = k >> 8, c = k & 255;
    Wob[g] = (ch < 27) ? f2bf(offset_w[((size_t)(ch * 256 + c)) * 9 + kidx])
                       : (unsigned short)0;
  } else if (gid < N1 + N2 + 128) {
    zp[gid - N1 - N2] = 0;
  }
}

// ---------------------------------------------------------------------------
// Kernel 3: offset conv as MFMA GEMM with implicit im2col.
//  O2[bhw][32] = sum_k Patch[bhw][k] * Wob[ch][k] + offb[ch]   (bias folded in)
// ---------------------------------------------------------------------------
__global__ __launch_bounds__(256) void k_offs_gemm(const unsigned short* __restrict__ xTb,
                                                   const unsigned short* __restrict__ Wob,
                                                   const unsigned short* __restrict__ zp,
                                                   const float* __restrict__ offb,
                                                   float* __restrict__ O2) {
  __shared__ unsigned short As[64 * 32];
  __shared__ unsigned short Bs[32 * 32];
  int t = threadIdx.x;
  int wv = t >> 6, lane = t & 63;
  int n0 = blockIdx.x * 64;
  int r0 = t >> 2, coff = (t & 3) * 8;

  int rowA = n0 + r0;
  int b_ = rowA >> 12, hw = rowA & 4095, h = hw >> 6, w = hw & 63;

  f32x4 acc[2] = {};
  char* AsB = (char*)As;
  char* BsB = (char*)Bs;

  for (int kt = 0; kt < 72; ++kt) {
    int k0 = kt * 32;
    int kidx = k0 >> 8, c0 = k0 & 255;
    int di = kidx / 3 - 1, dj = kidx % 3 - 1;
    {
      int y = h + di, xx = w + dj;
      const unsigned short* g = (y >= 0 && y < 64 && xx >= 0 && xx < 64)
          ? xTb + (((((size_t)b_) << 12) + (y << 6) + xx) << 8) + c0 + coff
          : zp;
      gl2lds16(g, AsB + wv * 1024);
    }
    if (t < 128) {
      const unsigned short* g = Wob + (size_t)(t >> 2) * KDIM + k0 + coff;
      gl2lds16(g, BsB + wv * 1024);
    }
    __syncthreads();
    bf16x8 aF, bF[2];
    aF = *(const bf16x8*)(As + (wv * 16 + (lane & 15)) * 32 + (lane >> 4) * 8);
#pragma unroll
    for (int j = 0; j < 2; ++j)
      bF[j] = *(const bf16x8*)(Bs + (j * 16 + (lane & 15)) * 32 + (lane >> 4) * 8);
#pragma unroll
    for (int j = 0; j < 2; ++j)
      acc[j] = __builtin_amdgcn_mfma_f32_16x16x32_bf16(aF, bF[j], acc[j], 0, 0, 0);
    __syncthreads();
  }

  int quad = lane >> 4, cl = lane & 15;
#pragma unroll
  for (int j = 0; j < 2; ++j) {
    int col = j * 16 + cl;
    float bias = (col < 27) ? offb[col] : 0.f;
#pragma unroll
    for (int r = 0; r < 4; ++r) {
      int row = n0 + wv * 16 + quad * 4 + r;
      O2[(size_t)row * 32 + col] = acc[j][r] + bias;
    }
  }
}

// ---------------------------------------------------------------------------
// Kernel 4: sampling weights/offsets table.
//  SW[k][bhw] = {w00,w01,w10,w11 (mask*validity folded), off00..off11 (elem)}
// ---------------------------------------------------------------------------
__global__ __launch_bounds__(256) void k_sweights(const float* __restrict__ O2,
                                                  float* __restrict__ SW) {
  int gid = blockIdx.x * 256 + threadIdx.x;   // 9*16384 items, k-major
  if (gid >= 9 * 16384) return;
  int k = gid >> 14;
  int bhw = gid & 16383;
  int h = (bhw >> 6) & 63, w = bhw & 63;

  const float* o = O2 + (size_t)bhw * 32;
  float dy = o[2 * k];
  float dx = o[2 * k + 1];
  float mv = o[18 + k];
  float mask = 1.0f / (1.0f + expf(-mv));

  float py = (float)(h - 1 + k / 3) + dy;
  float px = (float)(w - 1 + k % 3) + dx;
  float y0f = floorf(py), x0f = floorf(px);
  float wy = py - y0f, wx = px - x0f;
  int y0 = (int)y0f, x0 = (int)x0f;
  int y1 = y0 + 1, x1 = x0 + 1;

  float vy0 = (y0 >= 0 && y0 < 64) ? 1.f : 0.f;
  float vy1 = (y1 >= 0 && y1 < 64) ? 1.f : 0.f;
  float vx0 = (x0 >= 0 && x0 < 64) ? 1.f : 0.f;
  float vx1 = (x1 >= 0 && x1 < 64) ? 1.f : 0.f;
  int y0c = min(max(y0, 0), 63), y1c = min(max(y1, 0), 63);
  int x0c = min(max(x0, 0), 63), x1c = min(max(x1, 0), 63);

  float4 wv4;
  wv4.x = (1.f - wy) * (1.f - wx) * vy0 * vx0 * mask;
  wv4.y = (1.f - wy) * wx * vy0 * vx1 * mask;
  wv4.z = wy * (1.f - wx) * vy1 * vx0 * mask;
  wv4.w = wy * wx * vy1 * vx1 * mask;
  uint4 ov;
  ov.x = (unsigned)(((y0c << 6) + x0c) << 8);
  ov.y = (unsigned)(((y0c << 6) + x1c) << 8);
  ov.z = (unsigned)(((y1c << 6) + x0c) << 8);
  ov.w = (unsigned)(((y1c << 6) + x1c) << 8);

  float* p = SW + (size_t)gid * 8;
  *(float4*)p = wv4;
  *(uint4*)(p + 4) = ov;
}

// ---------------------------------------------------------------------------
// Kernel 5: fused sample + main GEMM.
//  out[(b,o,hw)] = sum_k Wb[o][k] * sample(xTb, SW)[bhw][k]
//  Tile BM=256 (full M) x BN=64 x BK=32. Grid 256 blocks, 512 thr (8 waves).
//  Wave grid 4(m) x 2(n); wave = 64x32 (acc 4x2). S never materialized.
// ---------------------------------------------------------------------------
__global__ __launch_bounds__(512) void k_fused(const unsigned short* __restrict__ Wb,
                                               const unsigned short* __restrict__ xTb,
                                               const float* __restrict__ SW,
                                               float* __restrict__ out) {
  __shared__ unsigned short As[256 * 32];   // 16 KB, Wb tile (lds-direct layout)
  __shared__ unsigned short Bs[64 * 40];    // 5 KB, sampled tile, rows padded to 40
  int t = threadIdx.x;
  int wv = t >> 6, lane = t & 63;
  int n0 = blockIdx.x * 64;
  int b  = n0 >> 12;                        // uniform per block (4096 % 64 == 0)
  const unsigned short* xb = xTb + ((size_t)b << 20);
  int wm = wv >> 1, wn = wv & 1;

  // A staging: wave wv stages rows [wv*16, wv*16+16) and +128 (two issues)
  int arow = wv * 16 + (lane >> 2);
  const unsigned short* gA0 = Wb + (size_t)arow * KDIM + (lane & 3) * 8;
  const unsigned short* gA1 = gA0 + (size_t)128 * KDIM;
  char* AsB = (char*)As;
  unsigned adst0 = wv * 1024;
  unsigned adst1 = 8192 + wv * 1024;

  // B sampling role: row r (0..63), channel group g (0..7) -> ch = g*4
  int r = t >> 3, g = t & 7;
  int ch0 = g * 4;

  f32x4 acc[4][2] = {};
  float w00 = 0, w01 = 0, w10 = 0, w11 = 0;
  const unsigned short *p00 = xb, *p01 = xb, *p10 = xb, *p11 = xb;

  for (int kt = 0; kt < 72; ++kt) {
    if ((kt & 7) == 0) {
      int kidx = kt >> 3;
      const float* sw = SW + ((size_t)((kidx << 14) + n0 + r)) * 8;
      float4 wv4 = *(const float4*)sw;
      uint4  ov  = *(const uint4*)(sw + 4);
      w00 = wv4.x; w01 = wv4.y; w10 = wv4.z; w11 = wv4.w;
      p00 = xb + ov.x + ch0; p01 = xb + ov.y + ch0;
      p10 = xb + ov.z + ch0; p11 = xb + ov.w + ch0;
    }
    int k0 = kt * 32;
    gl2lds16(gA0 + k0, AsB + adst0);
    gl2lds16(gA1 + k0, AsB + adst1);

    ushort4 q00 = *(const ushort4*)p00;
    ushort4 q01 = *(const ushort4*)p01;
    ushort4 q10 = *(const ushort4*)p10;
    ushort4 q11 = *(const ushort4*)p11;
    float s0 = w00 * bf2f(q00.x) + w01 * bf2f(q01.x) + w10 * bf2f(q10.x) + w11 * bf2f(q11.x);
    float s1 = w00 * bf2f(q00.y) + w01 * bf2f(q01.y) + w10 * bf2f(q10.y) + w11 * bf2f(q11.y);
    float s2 = w00 * bf2f(q00.z) + w01 * bf2f(q01.z) + w10 * bf2f(q10.z) + w11 * bf2f(q11.z);
    float s3 = w00 * bf2f(q00.w) + w01 * bf2f(q01.w) + w10 * bf2f(q10.w) + w11 * bf2f(q11.w);
    ushort4 rr;
    rr.x = f2bf(s0); rr.y = f2bf(s1); rr.z = f2bf(s2); rr.w = f2bf(s3);
    *(ushort4*)(Bs + r * 40 + ch0) = rr;

    __syncthreads();
    bf16x8 aF[4], bF[2];
#pragma unroll
    for (int i = 0; i < 4; ++i)
      aF[i] = *(const bf16x8*)(As + (wm * 64 + i * 16 + (lane & 15)) * 32 + (lane >> 4) * 8);
#pragma unroll
    for (int j = 0; j < 2; ++j)
      bF[j] = *(const bf16x8*)(Bs + (wn * 32 + j * 16 + (lane & 15)) * 40 + (lane >> 4) * 8);
#pragma unroll
    for (int i = 0; i < 4; ++i)
#pragma unroll
      for (int j = 0; j < 2; ++j)
        acc[i][j] = __builtin_amdgcn_mfma_f32_16x16x32_bf16(aF[i], bF[j], acc[i][j], 0, 0, 0);
    __syncthreads();
    p00 += 32; p01 += 32; p10 += 32; p11 += 32;
  }

  int quad = lane >> 4, cl = lane & 15;
  float* ob = out + (((size_t)b) << 20);
#pragma unroll
  for (int i = 0; i < 4; ++i) {
    int mbase = wm * 64 + i * 16 + quad * 4;
#pragma unroll
    for (int j = 0; j < 2; ++j) {
      int ncol = n0 + wn * 32 + j * 16 + cl;
      int hw = ncol & 4095;
      float* op = ob + hw;
#pragma unroll
      for (int rr2 = 0; rr2 < 4; ++rr2) {
        op[((size_t)(mbase + rr2)) << 12] = acc[i][j][rr2];
      }
    }
  }
}

// ---------------------------------------------------------------------------
extern "C" void kernel_launch(void* const* d_in, const int* in_sizes, int n_in,
                              void* d_out, int out_size, void* d_ws, size_t ws_size,
                              hipStream_t stream) {
  const float* x        = (const float*)d_in[0];
  const float* offset_w = (const float*)d_in[1];
  const float* offset_b = (const float*)d_in[2];
  const float* dcn_w    = (const float*)d_in[3];
  float* out = (float*)d_out;

  char* ws = (char*)d_ws;
  size_t off = 0;
  auto carve = [&](size_t bytes) -> void* {
    void* p = ws + off;
    off += (bytes + 255) & ~(size_t)255;
    return p;
  };
  unsigned short* xTb = (unsigned short*)carve(4ull * 64 * 64 * 256 * 2);   // 8 MB
  unsigned short* Wb  = (unsigned short*)carve(256ull * KDIM * 2);          // 1.125 MB
  unsigned short* Wob = (unsigned short*)carve(32ull * KDIM * 2);           // 144 KB
  unsigned short* zp  = (unsigned short*)carve(256);                        // zero page
  float*          O2  = (float*)carve(16384ull * 32 * 4);                   // 2 MB
  float*          SW  = (float*)carve(9ull * 16384 * 8 * 4);                // 4.7 MB
  (void)ws_size; (void)in_sizes; (void)n_in; (void)out_size;

  k_transpose<<<dim3(128, 8, 4), 256, 0, stream>>>(x, xTb);
  k_wprep<<<dim3((256 * KDIM + 32 * KDIM + 128 + 255) / 256), 256, 0, stream>>>(
      dcn_w, offset_w, Wb, Wob, zp);
  k_offs_gemm<<<dim3(256), 256, 0, stream>>>(xTb, Wob, zp, offset_b, O2);
  k_sweights<<<dim3((9 * 16384 + 255) / 256), 256, 0, stream>>>(O2, SW);
  k_fused<<<dim3(256), 512, 0, stream>>>(Wb, xTb, SW, out);
}

// Round 4
// 161.324 us; speedup vs baseline: 1.1570x; 1.1570x over previous
//
#include <hip/hip_runtime.h>
#include <hip/hip_bf16.h>
#include <stdint.h>
#include <math.h>

#define KDIM 2304   // 9 * 256

typedef __attribute__((ext_vector_type(8))) short bf16x8;
typedef __attribute__((ext_vector_type(8))) unsigned short u16x8;
typedef __attribute__((ext_vector_type(4))) float f32x4;

__device__ inline unsigned short f2bf(float f) {
  union { float f; unsigned int u; } v; v.f = f;
  unsigned int u = v.u;
  unsigned int r = (u + 0x7FFFu + ((u >> 16) & 1u)) >> 16;
  return (unsigned short)r;
}
__device__ inline float bf2f(unsigned short h) {
  union { unsigned int u; float f; } v; v.u = ((unsigned int)h) << 16;
  return v.f;
}

__device__ inline void gl2lds16(const void* g, void* l) {
  __builtin_amdgcn_global_load_lds((const __attribute__((address_space(1))) void*)g,
                                   (__attribute__((address_space(3))) void*)l,
                                   16, 0, 0);
}

// ---------------------------------------------------------------------------
// Kernel 1: x (B,C,H,W) fp32 -> xTb (B,H,W,C) bf16
// ---------------------------------------------------------------------------
__global__ __launch_bounds__(256) void k_transpose(const float* __restrict__ x,
                                                   unsigned short* __restrict__ xTb) {
  __shared__ float tile[32][33];
  int t = threadIdx.x;
  int tx = t & 31, ty = t >> 5;
  int p0 = blockIdx.x * 32;
  int c0 = blockIdx.y * 32;
  int b  = blockIdx.z;
  const float* xb = x + ((size_t)b << 20);
#pragma unroll
  for (int i = 0; i < 4; ++i) {
    int c = c0 + ty + i * 8;
    tile[ty + i * 8][tx] = xb[((size_t)c << 12) + p0 + tx];
  }
  __syncthreads();
  unsigned short* ob = xTb + ((size_t)b << 20);
#pragma unroll
  for (int i = 0; i < 4; ++i) {
    int p = p0 + ty + i * 8;
    ob[(((size_t)p) << 8) + c0 + tx] = f2bf(tile[tx][ty + i * 8]);
  }
}

// ---------------------------------------------------------------------------
// Kernel 2: weight prep.
//  Wpk: dcn_w packed in A-fragment order:
//    Wpk[((kc*16 + mb)*64 + lane)*8 + j] = dcn_w[row=mb*16+(lane&15)]
//        [c=(gk&255)][kidx=gk>>8],  gk = kc*32 + (lane>>4)*8 + j
//  Wob[ch][k*256+c] = bf16(offset_w), zp = zero page.
// ---------------------------------------------------------------------------
__global__ __launch_bounds__(256) void k_wprep(const float* __restrict__ dcn_w,
                                               const float* __restrict__ offset_w,
                                               unsigned short* __restrict__ Wpk,
                                               unsigned short* __restrict__ Wob,
                                               unsigned short* __restrict__ zp) {
  int gid = blockIdx.x * 256 + threadIdx.x;
  const int N1 = 72 * 8192;        // 589824 Wpk elements
  const int N2 = 32 * KDIM;        // Wob
  if (gid < N1) {
    int j = gid & 7;
    int lane = (gid >> 3) & 63;
    int mb = (gid >> 9) & 15;
    int kc = gid >> 13;
    int row = mb * 16 + (lane & 15);
    int gk = kc * 32 + ((lane >> 4) << 3) + j;
    int c = gk & 255, kidx = gk >> 8;
    Wpk[gid] = f2bf(dcn_w[((size_t)(row * 256 + c)) * 9 + kidx]);
  } else if (gid < N1 + N2) {
    int g = gid - N1;
    int ch = g / KDIM, k = g % KDIM;
    int kidx = k >> 8, c = k & 255;
    Wob[g] = (ch < 27) ? f2bf(offset_w[((size_t)(ch * 256 + c)) * 9 + kidx])
                       : (unsigned short)0;
  } else if (gid < N1 + N2 + 128) {
    zp[gid - N1 - N2] = 0;
  }
}

// ---------------------------------------------------------------------------
// Kernel 3: offset conv as MFMA GEMM with implicit im2col (bias folded).
// ---------------------------------------------------------------------------
__global__ __launch_bounds__(256) void k_offs_gemm(const unsigned short* __restrict__ xTb,
                                                   const unsigned short* __restrict__ Wob,
                                                   const unsigned short* __restrict__ zp,
                                                   const float* __restrict__ offb,
                                                   float* __restrict__ O2) {
  __shared__ unsigned short As[64 * 32];
  __shared__ unsigned short Bs[32 * 32];
  int t = threadIdx.x;
  int wv = t >> 6, lane = t & 63;
  int n0 = blockIdx.x * 64;
  int r0 = t >> 2, coff = (t & 3) * 8;

  int rowA = n0 + r0;
  int b_ = rowA >> 12, hw = rowA & 4095, h = hw >> 6, w = hw & 63;

  f32x4 acc[2] = {};
  char* AsB = (char*)As;
  char* BsB = (char*)Bs;

  for (int kt = 0; kt < 72; ++kt) {
    int k0 = kt * 32;
    int kidx = k0 >> 8, c0 = k0 & 255;
    int di = kidx / 3 - 1, dj = kidx % 3 - 1;
    {
      int y = h + di, xx = w + dj;
      const unsigned short* g = (y >= 0 && y < 64 && xx >= 0 && xx < 64)
          ? xTb + (((((size_t)b_) << 12) + (y << 6) + xx) << 8) + c0 + coff
          : zp;
      gl2lds16(g, AsB + wv * 1024);
    }
    if (t < 128) {
      const unsigned short* g = Wob + (size_t)(t >> 2) * KDIM + k0 + coff;
      gl2lds16(g, BsB + wv * 1024);
    }
    __syncthreads();
    bf16x8 aF, bF[2];
    aF = *(const bf16x8*)(As + (wv * 16 + (lane & 15)) * 32 + (lane >> 4) * 8);
#pragma unroll
    for (int j = 0; j < 2; ++j)
      bF[j] = *(const bf16x8*)(Bs + (j * 16 + (lane & 15)) * 32 + (lane >> 4) * 8);
#pragma unroll
    for (int j = 0; j < 2; ++j)
      acc[j] = __builtin_amdgcn_mfma_f32_16x16x32_bf16(aF, bF[j], acc[j], 0, 0, 0);
    __syncthreads();
  }

  int quad = lane >> 4, cl = lane & 15;
#pragma unroll
  for (int j = 0; j < 2; ++j) {
    int col = j * 16 + cl;
    float bias = (col < 27) ? offb[col] : 0.f;
#pragma unroll
    for (int r = 0; r < 4; ++r) {
      int row = n0 + wv * 16 + quad * 4 + r;
      O2[(size_t)row * 32 + col] = acc[j][r] + bias;
    }
  }
}

// ---------------------------------------------------------------------------
// Kernel 4: sampling weights/offsets table.
//  SW[k][bhw] = {w00,w01,w10,w11 (mask*validity), elem offsets of 4 corners}
// ---------------------------------------------------------------------------
__global__ __launch_bounds__(256) void k_sweights(const float* __restrict__ O2,
                                                  float* __restrict__ SW) {
  int gid = blockIdx.x * 256 + threadIdx.x;
  if (gid >= 9 * 16384) return;
  int k = gid >> 14;
  int bhw = gid & 16383;
  int h = (bhw >> 6) & 63, w = bhw & 63;

  const float* o = O2 + (size_t)bhw * 32;
  float dy = o[2 * k];
  float dx = o[2 * k + 1];
  float mv = o[18 + k];
  float mask = 1.0f / (1.0f + expf(-mv));

  float py = (float)(h - 1 + k / 3) + dy;
  float px = (float)(w - 1 + k % 3) + dx;
  float y0f = floorf(py), x0f = floorf(px);
  float wy = py - y0f, wx = px - x0f;
  int y0 = (int)y0f, x0 = (int)x0f;
  int y1 = y0 + 1, x1 = x0 + 1;

  float vy0 = (y0 >= 0 && y0 < 64) ? 1.f : 0.f;
  float vy1 = (y1 >= 0 && y1 < 64) ? 1.f : 0.f;
  float vx0 = (x0 >= 0 && x0 < 64) ? 1.f : 0.f;
  float vx1 = (x1 >= 0 && x1 < 64) ? 1.f : 0.f;
  int y0c = min(max(y0, 0), 63), y1c = min(max(y1, 0), 63);
  int x0c = min(max(x0, 0), 63), x1c = min(max(x1, 0), 63);

  float4 wv4;
  wv4.x = (1.f - wy) * (1.f - wx) * vy0 * vx0 * mask;
  wv4.y = (1.f - wy) * wx * vy0 * vx1 * mask;
  wv4.z = wy * (1.f - wx) * vy1 * vx0 * mask;
  wv4.w = wy * wx * vy1 * vx1 * mask;
  uint4 ov;
  ov.x = (unsigned)(((y0c << 6) + x0c) << 8);
  ov.y = (unsigned)(((y0c << 6) + x1c) << 8);
  ov.z = (unsigned)(((y1c << 6) + x0c) << 8);
  ov.w = (unsigned)(((y1c << 6) + x1c) << 8);

  float* p = SW + (size_t)gid * 8;
  *(float4*)p = wv4;
  *(uint4*)(p + 4) = ov;
}

// ---------------------------------------------------------------------------
// Kernel 5: fused sample + main GEMM, software-pipelined.
//  BM=256 (full M) x BN=64, BK=32. 256 thr / 4 waves; wave tile 64x64
//  (acc 4x4). A-fragments loaded DIRECTLY from Wpk (no LDS, no conflicts).
//  Sampled B tile through double-buffered padded LDS; gathers + A prefetched
//  one iteration ahead so global latency hides behind barrier + 16 MFMA.
// ---------------------------------------------------------------------------
__global__ __launch_bounds__(256) void k_fused(const unsigned short* __restrict__ Wpk,
                                               const unsigned short* __restrict__ xTb,
                                               const float* __restrict__ SW,
                                               float* __restrict__ out) {
  __shared__ __align__(16) unsigned short Bs[2][64 * 40];  // 10 KB, rows padded
  int t = threadIdx.x;
  int wv = t >> 6, lane = t & 63;
  int n0 = blockIdx.x * 64;
  int b  = n0 >> 12;                 // uniform per block
  const unsigned short* xb = xTb + ((size_t)b << 20);

  // sampling role: row r (0..63), channel octet g (0..3) -> ch = g*8
  int r = t >> 2, g = t & 3;
  int ch0 = g * 8;
  int bsw = r * 40 + ch0;

  // A-fragment base: wave wv covers m-blocks wv*4 .. wv*4+3
  const unsigned short* wpBase = Wpk + ((size_t)(wv * 4 * 64 + lane)) * 8;

  f32x4 acc[4][4] = {};

  float4 wv4; uint4 ov;
  {
    const float* sw = SW + ((size_t)(n0 + r)) * 8;
    wv4 = *(const float4*)sw;
    ov  = *(const uint4*)(sw + 4);
  }
  u16x8 q00, q01, q10, q11;
  bf16x8 aF[4], aFn[4];

  // prologue: gathers + A for kt = 0
  {
    int c = ch0;
    q00 = *(const u16x8*)(xb + ov.x + c);
    q01 = *(const u16x8*)(xb + ov.y + c);
    q10 = *(const u16x8*)(xb + ov.z + c);
    q11 = *(const u16x8*)(xb + ov.w + c);
#pragma unroll
    for (int i = 0; i < 4; ++i)
      aF[i] = *(const bf16x8*)(wpBase + (size_t)i * 512);
  }

#pragma unroll 2
  for (int kt = 0; kt < 72; ++kt) {
    // blend current gathers -> Bs[kt&1]
    float s[8];
#pragma unroll
    for (int c = 0; c < 8; ++c)
      s[c] = wv4.x * bf2f(q00[c]) + wv4.y * bf2f(q01[c])
           + wv4.z * bf2f(q10[c]) + wv4.w * bf2f(q11[c]);
    union { __hip_bfloat162 h2[4]; bf16x8 v; } pk;
#pragma unroll
    for (int c = 0; c < 4; ++c)
      pk.h2[c] = __float22bfloat162_rn(make_float2(s[2 * c], s[2 * c + 1]));
    *(bf16x8*)(&Bs[kt & 1][bsw]) = pk.v;

    // prefetch kt+1 (covered by barrier + MFMA below)
    if (kt < 71) {
      int kn = kt + 1;
      if ((kn & 7) == 0) {
        const float* sw = SW + ((size_t)(((kn >> 3) << 14) + n0 + r)) * 8;
        wv4 = *(const float4*)sw;
        ov  = *(const uint4*)(sw + 4);
      }
      int c = ((kn & 7) << 5) + ch0;
      q00 = *(const u16x8*)(xb + ov.x + c);
      q01 = *(const u16x8*)(xb + ov.y + c);
      q10 = *(const u16x8*)(xb + ov.z + c);
      q11 = *(const u16x8*)(xb + ov.w + c);
#pragma unroll
      for (int i = 0; i < 4; ++i)
        aFn[i] = *(const bf16x8*)(wpBase + ((size_t)kn * 16 + i) * 512);
    }

    __syncthreads();
    bf16x8 bF[4];
#pragma unroll
    for (int j = 0; j < 4; ++j)
      bF[j] = *(const bf16x8*)(&Bs[kt & 1][(j * 16 + (lane & 15)) * 40 + (lane >> 4) * 8]);
#pragma unroll
    for (int i = 0; i < 4; ++i)
#pragma unroll
      for (int j = 0; j < 4; ++j)
        acc[i][j] = __builtin_amdgcn_mfma_f32_16x16x32_bf16(aF[i], bF[j], acc[i][j], 0, 0, 0);
    if (kt < 71) {
#pragma unroll
      for (int i = 0; i < 4; ++i) aF[i] = aFn[i];
    }
  }

  // epilogue: C/D layout col=lane&15, row=quad*4+reg
  int quad = lane >> 4, cl = lane & 15;
  float* ob = out + (((size_t)b) << 20);
#pragma unroll
  for (int i = 0; i < 4; ++i) {
    int mbase = wv * 64 + i * 16 + quad * 4;
#pragma unroll
    for (int j = 0; j < 4; ++j) {
      int hw = (n0 & 4095) + j * 16 + cl;
      float* op = ob + hw;
#pragma unroll
      for (int rr = 0; rr < 4; ++rr)
        op[((size_t)(mbase + rr)) << 12] = acc[i][j][rr];
    }
  }
}

// ---------------------------------------------------------------------------
extern "C" void kernel_launch(void* const* d_in, const int* in_sizes, int n_in,
                              void* d_out, int out_size, void* d_ws, size_t ws_size,
                              hipStream_t stream) {
  const float* x        = (const float*)d_in[0];
  const float* offset_w = (const float*)d_in[1];
  const float* offset_b = (const float*)d_in[2];
  const float* dcn_w    = (const float*)d_in[3];
  float* out = (float*)d_out;

  char* ws = (char*)d_ws;
  size_t off = 0;
  auto carve = [&](size_t bytes) -> void* {
    void* p = ws + off;
    off += (bytes + 255) & ~(size_t)255;
    return p;
  };
  unsigned short* xTb = (unsigned short*)carve(4ull * 64 * 64 * 256 * 2);   // 8 MB
  unsigned short* Wpk = (unsigned short*)carve(72ull * 8192 * 2);           // 1.125 MB
  unsigned short* Wob = (unsigned short*)carve(32ull * KDIM * 2);           // 144 KB
  unsigned short* zp  = (unsigned short*)carve(256);                        // zero page
  float*          O2  = (float*)carve(16384ull * 32 * 4);                   // 2 MB
  float*          SW  = (float*)carve(9ull * 16384 * 8 * 4);                // 4.5 MB
  (void)ws_size; (void)in_sizes; (void)n_in; (void)out_size;

  k_transpose<<<dim3(128, 8, 4), 256, 0, stream>>>(x, xTb);
  k_wprep<<<dim3((72 * 8192 + 32 * KDIM + 128 + 255) / 256), 256, 0, stream>>>(
      dcn_w, offset_w, Wpk, Wob, zp);
  k_offs_gemm<<<dim3(256), 256, 0, stream>>>(xTb, Wob, zp, offset_b, O2);
  k_sweights<<<dim3((9 * 16384 + 255) / 256), 256, 0, stream>>>(O2, SW);
  k_fused<<<dim3(256), 256, 0, stream>>>(Wpk, xTb, SW, out);
}

// Round 5
// 153.402 us; speedup vs baseline: 1.2167x; 1.0516x over previous
//
#include <hip/hip_runtime.h>
#include <hip/hip_bf16.h>
#include <stdint.h>
#include <math.h>

#define KDIM 2304   // 9 * 256

typedef __attribute__((ext_vector_type(8))) short bf16x8;
typedef __attribute__((ext_vector_type(4))) float f32x4;

__device__ inline unsigned short f2bf(float f) {
  union { float f; unsigned int u; } v; v.f = f;
  unsigned int u = v.u;
  unsigned int r = (u + 0x7FFFu + ((u >> 16) & 1u)) >> 16;
  return (unsigned short)r;
}
__device__ inline float bf2f(unsigned short h) {
  union { unsigned int u; float f; } v; v.u = ((unsigned int)h) << 16;
  return v.f;
}

__device__ inline void gl2lds16(const void* g, void* l) {
  __builtin_amdgcn_global_load_lds((const __attribute__((address_space(1))) void*)g,
                                   (__attribute__((address_space(3))) void*)l,
                                   16, 0, 0);
}

// ---------------------------------------------------------------------------
// Kernel 1: x (B,C,H,W) fp32 -> xTb (B,H,W,C) bf16
// ---------------------------------------------------------------------------
__global__ __launch_bounds__(256) void k_transpose(const float* __restrict__ x,
                                                   unsigned short* __restrict__ xTb) {
  __shared__ float tile[32][33];
  int t = threadIdx.x;
  int tx = t & 31, ty = t >> 5;
  int p0 = blockIdx.x * 32;
  int c0 = blockIdx.y * 32;
  int b  = blockIdx.z;
  const float* xb = x + ((size_t)b << 20);
#pragma unroll
  for (int i = 0; i < 4; ++i) {
    int c = c0 + ty + i * 8;
    tile[ty + i * 8][tx] = xb[((size_t)c << 12) + p0 + tx];
  }
  __syncthreads();
  unsigned short* ob = xTb + ((size_t)b << 20);
#pragma unroll
  for (int i = 0; i < 4; ++i) {
    int p = p0 + ty + i * 8;
    ob[(((size_t)p) << 8) + c0 + tx] = f2bf(tile[tx][ty + i * 8]);
  }
}

// ---------------------------------------------------------------------------
// Kernel 2: weight prep (Wpk in A-fragment order; Wob; zero page).
// ---------------------------------------------------------------------------
__global__ __launch_bounds__(256) void k_wprep(const float* __restrict__ dcn_w,
                                               const float* __restrict__ offset_w,
                                               unsigned short* __restrict__ Wpk,
                                               unsigned short* __restrict__ Wob,
                                               unsigned short* __restrict__ zp) {
  int gid = blockIdx.x * 256 + threadIdx.x;
  const int N1 = 72 * 8192;
  const int N2 = 32 * KDIM;
  if (gid < N1) {
    int j = gid & 7;
    int lane = (gid >> 3) & 63;
    int mb = (gid >> 9) & 15;
    int kc = gid >> 13;
    int row = mb * 16 + (lane & 15);
    int gk = kc * 32 + ((lane >> 4) << 3) + j;
    int c = gk & 255, kidx = gk >> 8;
    Wpk[gid] = f2bf(dcn_w[((size_t)(row * 256 + c)) * 9 + kidx]);
  } else if (gid < N1 + N2) {
    int g = gid - N1;
    int ch = g / KDIM, k = g % KDIM;
    int kidx = k >> 8, c = k & 255;
    Wob[g] = (ch < 27) ? f2bf(offset_w[((size_t)(ch * 256 + c)) * 9 + kidx])
                       : (unsigned short)0;
  } else if (gid < N1 + N2 + 128) {
    zp[gid - N1 - N2] = 0;
  }
}

// ---------------------------------------------------------------------------
// Kernel 3: offset conv GEMM, split-K x2 (blockIdx.y = K-half).
//  O2p[z][bhw][32] = sum_{kt in half z} Patch * Wob   (no bias here)
// ---------------------------------------------------------------------------
__global__ __launch_bounds__(256) void k_offs_gemm(const unsigned short* __restrict__ xTb,
                                                   const unsigned short* __restrict__ Wob,
                                                   const unsigned short* __restrict__ zp,
                                                   float* __restrict__ O2p) {
  __shared__ unsigned short As[64 * 32];
  __shared__ unsigned short Bs[32 * 32];
  int t = threadIdx.x;
  int wv = t >> 6, lane = t & 63;
  int n0 = blockIdx.x * 64;
  int z = blockIdx.y;
  int r0 = t >> 2, coff = (t & 3) * 8;

  int rowA = n0 + r0;
  int b_ = rowA >> 12, hw = rowA & 4095, h = hw >> 6, w = hw & 63;

  f32x4 acc[2] = {};
  char* AsB = (char*)As;
  char* BsB = (char*)Bs;

  for (int kt = z * 36; kt < z * 36 + 36; ++kt) {
    int k0 = kt * 32;
    int kidx = k0 >> 8, c0 = k0 & 255;
    int di = kidx / 3 - 1, dj = kidx % 3 - 1;
    {
      int y = h + di, xx = w + dj;
      const unsigned short* g = (y >= 0 && y < 64 && xx >= 0 && xx < 64)
          ? xTb + (((((size_t)b_) << 12) + (y << 6) + xx) << 8) + c0 + coff
          : zp;
      gl2lds16(g, AsB + wv * 1024);
    }
    if (t < 128) {
      const unsigned short* g = Wob + (size_t)(t >> 2) * KDIM + k0 + coff;
      gl2lds16(g, BsB + wv * 1024);
    }
    __syncthreads();
    bf16x8 aF, bF[2];
    aF = *(const bf16x8*)(As + (wv * 16 + (lane & 15)) * 32 + (lane >> 4) * 8);
#pragma unroll
    for (int j = 0; j < 2; ++j)
      bF[j] = *(const bf16x8*)(Bs + (j * 16 + (lane & 15)) * 32 + (lane >> 4) * 8);
#pragma unroll
    for (int j = 0; j < 2; ++j)
      acc[j] = __builtin_amdgcn_mfma_f32_16x16x32_bf16(aF, bF[j], acc[j], 0, 0, 0);
    __syncthreads();
  }

  int quad = lane >> 4, cl = lane & 15;
  float* O2z = O2p + (size_t)z * 16384 * 32;
#pragma unroll
  for (int j = 0; j < 2; ++j) {
    int col = j * 16 + cl;
#pragma unroll
    for (int r = 0; r < 4; ++r) {
      int row = n0 + wv * 16 + quad * 4 + r;
      O2z[(size_t)row * 32 + col] = acc[j][r];
    }
  }
}

// ---------------------------------------------------------------------------
// Kernel 4: sampling weights/offsets table (sums split-K partials + bias).
// ---------------------------------------------------------------------------
__global__ __launch_bounds__(256) void k_sweights(const float* __restrict__ O2p,
                                                  const float* __restrict__ offb,
                                                  float* __restrict__ SW) {
  int gid = blockIdx.x * 256 + threadIdx.x;
  if (gid >= 9 * 16384) return;
  int k = gid >> 14;
  int bhw = gid & 16383;
  int h = (bhw >> 6) & 63, w = bhw & 63;

  const float* o0 = O2p + (size_t)bhw * 32;
  const float* o1 = o0 + (size_t)16384 * 32;
  float dy = o0[2 * k]     + o1[2 * k]     + offb[2 * k];
  float dx = o0[2 * k + 1] + o1[2 * k + 1] + offb[2 * k + 1];
  float mv = o0[18 + k]    + o1[18 + k]    + offb[18 + k];
  float mask = 1.0f / (1.0f + expf(-mv));

  float py = (float)(h - 1 + k / 3) + dy;
  float px = (float)(w - 1 + k % 3) + dx;
  float y0f = floorf(py), x0f = floorf(px);
  float wy = py - y0f, wx = px - x0f;
  int y0 = (int)y0f, x0 = (int)x0f;
  int y1 = y0 + 1, x1 = x0 + 1;

  float vy0 = (y0 >= 0 && y0 < 64) ? 1.f : 0.f;
  float vy1 = (y1 >= 0 && y1 < 64) ? 1.f : 0.f;
  float vx0 = (x0 >= 0 && x0 < 64) ? 1.f : 0.f;
  float vx1 = (x1 >= 0 && x1 < 64) ? 1.f : 0.f;
  int y0c = min(max(y0, 0), 63), y1c = min(max(y1, 0), 63);
  int x0c = min(max(x0, 0), 63), x1c = min(max(x1, 0), 63);

  float4 wv4;
  wv4.x = (1.f - wy) * (1.f - wx) * vy0 * vx0 * mask;
  wv4.y = (1.f - wy) * wx * vy0 * vx1 * mask;
  wv4.z = wy * (1.f - wx) * vy1 * vx0 * mask;
  wv4.w = wy * wx * vy1 * vx1 * mask;
  uint4 ov;
  ov.x = (unsigned)(((y0c << 6) + x0c) << 8);
  ov.y = (unsigned)(((y0c << 6) + x1c) << 8);
  ov.z = (unsigned)(((y1c << 6) + x0c) << 8);
  ov.w = (unsigned)(((y1c << 6) + x1c) << 8);

  float* p = SW + (size_t)gid * 8;
  *(float4*)p = wv4;
  *(uint4*)(p + 4) = ov;
}

// ---------------------------------------------------------------------------
// Kernel 5: fused sample + main GEMM, software-pipelined, 512 thr / 8 waves.
//  BM=256 x BN=64, BK=32, grid 256 -> 2 waves/SIMD.
//  Wave tile 64x32 (acc 4x2): wm = wv&3, wn = wv>>2.
//  A-fragments direct from Wpk (no LDS); B double-buffered padded LDS.
// ---------------------------------------------------------------------------
__global__ __launch_bounds__(512) void k_fused(const unsigned short* __restrict__ Wpk,
                                               const unsigned short* __restrict__ xTb,
                                               const float* __restrict__ SW,
                                               float* __restrict__ out) {
  __shared__ __align__(16) unsigned short Bs[2][64 * 40];  // 10 KB
  int t = threadIdx.x;
  int wv = t >> 6, lane = t & 63;
  int wm = wv & 3, wn = wv >> 2;
  int n0 = blockIdx.x * 64;
  int b  = n0 >> 12;
  const unsigned short* xb = xTb + ((size_t)b << 20);

  // sampling role: row r (0..63), channel quad g (0..7) -> ch = g*4
  int r = t >> 3, g = t & 7;
  int ch0 = g * 4;
  int bsw = r * 40 + ch0;

  // A-fragment base: wave covers m-blocks wm*4 .. wm*4+3
  const unsigned short* wpBase = Wpk + ((size_t)(wm * 4 * 64 + lane)) * 8;

  f32x4 acc[4][2] = {};

  float4 wv4; uint4 ov;
  {
    const float* sw = SW + ((size_t)(n0 + r)) * 8;
    wv4 = *(const float4*)sw;
    ov  = *(const uint4*)(sw + 4);
  }
  ushort4 q00, q01, q10, q11;
  bf16x8 aF[4], aFn[4];

  // prologue: gathers + A for kt = 0
  {
    unsigned c = (unsigned)ch0;
    q00 = *(const ushort4*)(xb + ov.x + c);
    q01 = *(const ushort4*)(xb + ov.y + c);
    q10 = *(const ushort4*)(xb + ov.z + c);
    q11 = *(const ushort4*)(xb + ov.w + c);
#pragma unroll
    for (int i = 0; i < 4; ++i)
      aF[i] = *(const bf16x8*)(wpBase + (size_t)i * 512);
  }

#pragma unroll 2
  for (int kt = 0; kt < 72; ++kt) {
    // blend current gathers -> Bs[kt&1]
    float s[4];
    s[0] = wv4.x * bf2f(q00.x) + wv4.y * bf2f(q01.x) + wv4.z * bf2f(q10.x) + wv4.w * bf2f(q11.x);
    s[1] = wv4.x * bf2f(q00.y) + wv4.y * bf2f(q01.y) + wv4.z * bf2f(q10.y) + wv4.w * bf2f(q11.y);
    s[2] = wv4.x * bf2f(q00.z) + wv4.y * bf2f(q01.z) + wv4.z * bf2f(q10.z) + wv4.w * bf2f(q11.z);
    s[3] = wv4.x * bf2f(q00.w) + wv4.y * bf2f(q01.w) + wv4.z * bf2f(q10.w) + wv4.w * bf2f(q11.w);
    union { __hip_bfloat162 h2[2]; ushort4 v; } pk;
    pk.h2[0] = __float22bfloat162_rn(make_float2(s[0], s[1]));
    pk.h2[1] = __float22bfloat162_rn(make_float2(s[2], s[3]));
    *(ushort4*)(&Bs[kt & 1][bsw]) = pk.v;

    // prefetch kt+1 (covered by barrier + MFMA below)
    if (kt < 71) {
      int kn = kt + 1;
      if ((kn & 7) == 0) {
        const float* sw = SW + ((size_t)(((kn >> 3) << 14) + n0 + r)) * 8;
        wv4 = *(const float4*)sw;
        ov  = *(const uint4*)(sw + 4);
      }
      unsigned c = (unsigned)(((kn & 7) << 5) + ch0);
      q00 = *(const ushort4*)(xb + ov.x + c);
      q01 = *(const ushort4*)(xb + ov.y + c);
      q10 = *(const ushort4*)(xb + ov.z + c);
      q11 = *(const ushort4*)(xb + ov.w + c);
#pragma unroll
      for (int i = 0; i < 4; ++i)
        aFn[i] = *(const bf16x8*)(wpBase + ((size_t)kn * 16 + i) * 512);
    }

    __syncthreads();
    bf16x8 bF[2];
#pragma unroll
    for (int j = 0; j < 2; ++j)
      bF[j] = *(const bf16x8*)(&Bs[kt & 1][(wn * 32 + j * 16 + (lane & 15)) * 40 + (lane >> 4) * 8]);
#pragma unroll
    for (int i = 0; i < 4; ++i)
#pragma unroll
      for (int j = 0; j < 2; ++j)
        acc[i][j] = __builtin_amdgcn_mfma_f32_16x16x32_bf16(aF[i], bF[j], acc[i][j], 0, 0, 0);
    if (kt < 71) {
#pragma unroll
      for (int i = 0; i < 4; ++i) aF[i] = aFn[i];
    }
  }

  // epilogue
  int quad = lane >> 4, cl = lane & 15;
  float* ob = out + (((size_t)b) << 20);
#pragma unroll
  for (int i = 0; i < 4; ++i) {
    int mbase = wm * 64 + i * 16 + quad * 4;
#pragma unroll
    for (int j = 0; j < 2; ++j) {
      int hw = (n0 & 4095) + wn * 32 + j * 16 + cl;
      float* op = ob + hw;
#pragma unroll
      for (int rr = 0; rr < 4; ++rr)
        op[((size_t)(mbase + rr)) << 12] = acc[i][j][rr];
    }
  }
}

// ---------------------------------------------------------------------------
extern "C" void kernel_launch(void* const* d_in, const int* in_sizes, int n_in,
                              void* d_out, int out_size, void* d_ws, size_t ws_size,
                              hipStream_t stream) {
  const float* x        = (const float*)d_in[0];
  const float* offset_w = (const float*)d_in[1];
  const float* offset_b = (const float*)d_in[2];
  const float* dcn_w    = (const float*)d_in[3];
  float* out = (float*)d_out;

  char* ws = (char*)d_ws;
  size_t off = 0;
  auto carve = [&](size_t bytes) -> void* {
    void* p = ws + off;
    off += (bytes + 255) & ~(size_t)255;
    return p;
  };
  unsigned short* xTb = (unsigned short*)carve(4ull * 64 * 64 * 256 * 2);   // 8 MB
  unsigned short* Wpk = (unsigned short*)carve(72ull * 8192 * 2);           // 1.125 MB
  unsigned short* Wob = (unsigned short*)carve(32ull * KDIM * 2);           // 144 KB
  unsigned short* zp  = (unsigned short*)carve(256);                        // zero page
  float*          O2p = (float*)carve(2ull * 16384 * 32 * 4);               // 4 MB
  float*          SW  = (float*)carve(9ull * 16384 * 8 * 4);                // 4.5 MB
  (void)ws_size; (void)in_sizes; (void)n_in; (void)out_size;

  k_transpose<<<dim3(128, 8, 4), 256, 0, stream>>>(x, xTb);
  k_wprep<<<dim3((72 * 8192 + 32 * KDIM + 128 + 255) / 256), 256, 0, stream>>>(
      dcn_w, offset_w, Wpk, Wob, zp);
  k_offs_gemm<<<dim3(256, 2), 256, 0, stream>>>(xTb, Wob, zp, O2p);
  k_sweights<<<dim3((9 * 16384 + 255) / 256), 256, 0, stream>>>(O2p, offset_b, SW);
  k_fused<<<dim3(256), 512, 0, stream>>>(Wpk, xTb, SW, out);
}